// Round 5
// baseline (399.716 us; speedup 1.0000x reference)
//
#include <hip/hip_runtime.h>

#define COLS 16384
#define TPB  1024
#define CHUNK 8                                   // f32 elems per chunk
#define CPR  (COLS / CHUNK)                       // 2048 chunks per row
#define CPT  (CPR / TPB)                          // 2 chunks per thread
#define NW   (TPB / 64)                           // 16 waves
#define GRID 512                                  // 2 blocks/CU, persistent
#define LDSPAD(i) ((i) + ((i) >> 3))              // +1 float pad per 8 sums

// LDS-visibility barrier that does NOT drain vmcnt: prefetch loads and
// output stores stay in flight across it (unlike __syncthreads, which the
// compiler precedes with s_waitcnt vmcnt(0)).
__device__ __forceinline__ void lgkm_barrier() {
    asm volatile("s_waitcnt lgkmcnt(0)" ::: "memory");
    __builtin_amdgcn_s_barrier();
}

__global__ __launch_bounds__(TPB, 8) void revcumsum_rows(const float* __restrict__ x,
                                                         float* __restrict__ out,
                                                         int rows_per_block) {
    __shared__ float4 s_data[2][CPR];               // 65536 B
    __shared__ float  s_suf[CPR + (CPR >> 3)];      // 9216 B
    __shared__ float  s_wt[NW];                     // 64 B

    const int t    = threadIdx.x;
    const int lane = t & 63;
    const int w    = t >> 6;
    const long long row0 = (long long)blockIdx.x * rows_per_block;

    // Prologue: load first row into prefetch regs (chunk c = k*TPB + t).
    const float4* rp = reinterpret_cast<const float4*>(x + row0 * COLS);
    float4 ra0 = rp[2 * t];
    float4 rb0 = rp[2 * t + 1];
    float4 ra1 = rp[2 * (TPB + t)];
    float4 rb1 = rp[2 * (TPB + t) + 1];

    for (int it = 0; it < rows_per_block; ++it) {
        const long long row = row0 + it;

        // ---- Phase A: prefetch regs -> LDS, per-chunk fp32 sums.
        {
            const int c0 = t, c1 = TPB + t;
            s_data[0][c0] = ra0;  s_data[1][c0] = rb0;
            s_data[0][c1] = ra1;  s_data[1][c1] = rb1;
            s_suf[LDSPAD(c0)] = ((ra0.x + ra0.y) + (ra0.z + ra0.w))
                              + ((rb0.x + rb0.y) + (rb0.z + rb0.w));
            s_suf[LDSPAD(c1)] = ((ra1.x + ra1.y) + (ra1.z + ra1.w))
                              + ((rb1.x + rb1.y) + (rb1.z + rb1.w));
        }
        lgkm_barrier();                             // A -> B

        // ---- Prefetch row r+1 (in flight across scan + output phases).
        if (it + 1 < rows_per_block) {
            const float4* rpn = reinterpret_cast<const float4*>(x + (row + 1) * COLS);
            ra0 = rpn[2 * t];
            rb0 = rpn[2 * t + 1];
            ra1 = rpn[2 * (TPB + t)];
            rb1 = rpn[2 * (TPB + t) + 1];
        }

        // ---- Phase B: suffix-scan of the 2048 chunk sums.
        float segv[CPT];
        float T = 0.f;
        #pragma unroll
        for (int j = 0; j < CPT; ++j) {
            segv[j] = s_suf[LDSPAD(CPT * t + j)];
            T += segv[j];
        }
        float s = T;                                // wave-level inclusive suffix scan
        #pragma unroll
        for (int d = 1; d < 64; d <<= 1) {
            float o = __shfl_down(s, d);
            if (lane + d < 64) s += o;
        }
        if (lane == 0) s_wt[w] = s;                 // wave total
        lgkm_barrier();                             // publish s_wt
        float wave_off = 0.f;
        #pragma unroll
        for (int w2 = 0; w2 < NW; ++w2)
            if (w2 > w) wave_off += s_wt[w2];       // broadcast reads
        float running = (s - T) + wave_off;         // exclusive suffix over threads > t
        #pragma unroll
        for (int j = CPT - 1; j >= 0; --j) {
            const int idx = LDSPAD(CPT * t + j);
            const float v = segv[j];
            s_suf[idx] = running;                   // per-chunk exclusive suffix
            running += v;
        }
        lgkm_barrier();                             // B -> C

        // ---- Phase C: reverse cumsum per chunk from LDS, coalesced stores.
        float4* op = reinterpret_cast<float4*>(out + row * COLS);
        #pragma unroll
        for (int k = 0; k < CPT; ++k) {
            const int c = k * TPB + t;
            const float4 a = s_data[0][c];
            const float4 b = s_data[1][c];
            const float off = s_suf[LDSPAD(c)];
            float f[CHUNK] = {a.x, a.y, a.z, a.w, b.x, b.y, b.z, b.w};
            float acc = off;
            float o[CHUNK];
            #pragma unroll
            for (int j = CHUNK - 1; j >= 0; --j) {
                acc += f[j];
                o[j] = acc;
            }
            op[2 * c]     = make_float4(o[0], o[1], o[2], o[3]);
            op[2 * c + 1] = make_float4(o[4], o[5], o[6], o[7]);
        }
        lgkm_barrier();                             // C -> A' (s_data/s_suf reuse)
    }
}

extern "C" void kernel_launch(void* const* d_in, const int* in_sizes, int n_in,
                              void* d_out, int out_size, void* d_ws, size_t ws_size,
                              hipStream_t stream) {
    const float* x = (const float*)d_in[0];
    float* out = (float*)d_out;
    const int rows = in_sizes[0] / COLS;            // 16384
    const int rows_per_block = rows / GRID;         // 32
    revcumsum_rows<<<GRID, TPB, 0, stream>>>(x, out, rows_per_block);
}

// Round 7
// 377.863 us; speedup vs baseline: 1.0578x; 1.0578x over previous
//
#include <hip/hip_runtime.h>

#define COLS 16384
#define TPB  1024
#define CHUNK 8                                   // f32 elems per chunk
#define CPR  (COLS / CHUNK)                       // 2048 chunks per row
#define CPT  (CPR / TPB)                          // 2 chunks per thread
#define NW   (TPB / 64)                           // 16 waves
#define LDSPAD(i) ((i) + ((i) >> 3))              // +1 float pad per 8 sums

typedef float f4 __attribute__((ext_vector_type(4)));   // native vector: OK for nontemporal builtins

__global__ __launch_bounds__(TPB) void revcumsum_rows(const float* __restrict__ x,
                                                      float* __restrict__ out) {
    // Row data staged in LDS: 64KB + 9.2KB -> 2 blocks/CU, 32 waves/CU.
    __shared__ f4    s_data[2][CPR];                // 65536 B
    __shared__ float s_suf[CPR + (CPR >> 3)];       // 9216 B
    __shared__ float s_wt[NW];                      // 64 B

    const int t = threadIdx.x;
    const long long row = blockIdx.x;
    const f4* __restrict__ rowp4 = reinterpret_cast<const f4*>(x + row * (long long)COLS);
    f4* __restrict__       outp4 = reinterpret_cast<f4*>(out + row * (long long)COLS);

    // ---- Phase A: nontemporal streaming loads -> LDS, per-chunk fp32 sums.
    #pragma unroll
    for (int k = 0; k < CPT; ++k) {
        const int c = k * TPB + t;
        const f4 a = __builtin_nontemporal_load(rowp4 + 2 * c);
        const f4 b = __builtin_nontemporal_load(rowp4 + 2 * c + 1);
        s_data[0][c] = a;
        s_data[1][c] = b;
        const float s0 = (a.x + a.y) + (a.z + a.w);
        const float s1 = (b.x + b.y) + (b.z + b.w);
        s_suf[LDSPAD(c)] = s0 + s1;
    }
    __syncthreads();

    // ---- Phase B: thread t owns contiguous chunks [2t, 2t+2).
    float segv[CPT];
    float T = 0.f;
    #pragma unroll
    for (int j = 0; j < CPT; ++j) {
        segv[j] = s_suf[LDSPAD(CPT * t + j)];
        T += segv[j];
    }
    // Wave-level inclusive SUFFIX scan across 64 lanes.
    const int lane = t & 63;
    const int w    = t >> 6;
    float s = T;
    #pragma unroll
    for (int d = 1; d < 64; d <<= 1) {
        float o = __shfl_down(s, d);
        if (lane + d < 64) s += o;
    }
    if (lane == 0) s_wt[w] = s;                     // lane 0's inclusive suffix == wave total
    __syncthreads();
    float wave_off = 0.f;
    #pragma unroll
    for (int w2 = 0; w2 < NW; ++w2)
        if (w2 > w) wave_off += s_wt[w2];           // same-address reads -> broadcast
    float running = (s - T) + wave_off;             // exclusive suffix over threads > t

    #pragma unroll
    for (int j = CPT - 1; j >= 0; --j) {
        const int idx = LDSPAD(CPT * t + j);
        const float v = segv[j];
        s_suf[idx] = running;                       // per-chunk exclusive suffix
        running += v;
    }
    __syncthreads();

    // ---- Phase C: reverse cumsum per chunk from LDS, nontemporal streaming stores.
    #pragma unroll
    for (int k = 0; k < CPT; ++k) {
        const int c = k * TPB + t;
        const f4 a = s_data[0][c];
        const f4 b = s_data[1][c];
        const float off = s_suf[LDSPAD(c)];
        float f[CHUNK] = {a.x, a.y, a.z, a.w, b.x, b.y, b.z, b.w};
        float acc = off;
        float o[CHUNK];
        #pragma unroll
        for (int j = CHUNK - 1; j >= 0; --j) {
            acc += f[j];
            o[j] = acc;
        }
        f4 o0 = {o[0], o[1], o[2], o[3]};
        f4 o1 = {o[4], o[5], o[6], o[7]};
        __builtin_nontemporal_store(o0, outp4 + 2 * c);
        __builtin_nontemporal_store(o1, outp4 + 2 * c + 1);
    }
}

extern "C" void kernel_launch(void* const* d_in, const int* in_sizes, int n_in,
                              void* d_out, int out_size, void* d_ws, size_t ws_size,
                              hipStream_t stream) {
    const float* x = (const float*)d_in[0];
    float* out = (float*)d_out;
    const int rows = in_sizes[0] / COLS;   // 16384
    revcumsum_rows<<<rows, TPB, 0, stream>>>(x, out);
}

// Round 8
// 372.707 us; speedup vs baseline: 1.0725x; 1.0138x over previous
//
#include <hip/hip_runtime.h>

#define COLS 16384
#define TPB  1024
#define CHUNK 8                                   // f32 elems per chunk
#define CPR  (COLS / CHUNK)                       // 2048 chunks per row
#define NW   (TPB / 64)                           // 16 waves

typedef float f4 __attribute__((ext_vector_type(4)));

__global__ __launch_bounds__(TPB) void revcumsum_rows(const float* __restrict__ x,
                                                      float* __restrict__ out) {
    // Register-resident row data; LDS = 2x16 wave totals only. One barrier.
    __shared__ float s_wt0[NW];
    __shared__ float s_wt1[NW];

    const int t    = threadIdx.x;
    const int lane = t & 63;
    const int w    = t >> 6;
    const long long row = blockIdx.x;
    const f4* __restrict__ rowp4 = reinterpret_cast<const f4*>(x + row * (long long)COLS);
    f4* __restrict__       outp4 = reinterpret_cast<f4*>(out + row * (long long)COLS);

    // ---- Load both chunks (c0 = t, c1 = TPB + t) nontemporally into regs.
    const f4 a0 = __builtin_nontemporal_load(rowp4 + 2 * t);
    const f4 b0 = __builtin_nontemporal_load(rowp4 + 2 * t + 1);
    const f4 a1 = __builtin_nontemporal_load(rowp4 + 2 * (TPB + t));
    const f4 b1 = __builtin_nontemporal_load(rowp4 + 2 * (TPB + t) + 1);

    // Per-chunk fp32 sums (no LDS needed — data is ours).
    const float v0 = ((a0.x + a0.y) + (a0.z + a0.w)) + ((b0.x + b0.y) + (b0.z + b0.w));
    const float v1 = ((a1.x + a1.y) + (a1.z + a1.w)) + ((b1.x + b1.y) + (b1.z + b1.w));

    // ---- Paired wave-level inclusive SUFFIX scan over thread index.
    float s0 = v0, s1 = v1;
    #pragma unroll
    for (int d = 1; d < 64; d <<= 1) {
        const float o0 = __shfl_down(s0, d);
        const float o1 = __shfl_down(s1, d);
        if (lane + d < 64) { s0 += o0; s1 += o1; }
    }
    if (lane == 0) { s_wt0[w] = s0; s_wt1[w] = s1; }   // wave totals
    __syncthreads();

    // Cross-wave suffix offsets + grand total of the k=1 half.
    float off0 = 0.f, off1 = 0.f, total1 = 0.f;
    #pragma unroll
    for (int w2 = 0; w2 < NW; ++w2) {
        const float t1 = s_wt1[w2];                    // broadcast reads
        total1 += t1;
        if (w2 > w) { off0 += s_wt0[w2]; off1 += t1; }
    }
    // Exclusive suffixes: chunk t sees all chunks >t in k=0 plus ALL of k=1.
    const float E0 = (s0 - v0) + off0 + total1;
    const float E1 = (s1 - v1) + off1;

    // ---- In-register reverse cumsum per chunk, nontemporal streaming stores.
    {
        const float f[CHUNK] = {a0.x, a0.y, a0.z, a0.w, b0.x, b0.y, b0.z, b0.w};
        float acc = E0, o[CHUNK];
        #pragma unroll
        for (int j = CHUNK - 1; j >= 0; --j) { acc += f[j]; o[j] = acc; }
        f4 q0 = {o[0], o[1], o[2], o[3]};
        f4 q1 = {o[4], o[5], o[6], o[7]};
        __builtin_nontemporal_store(q0, outp4 + 2 * t);
        __builtin_nontemporal_store(q1, outp4 + 2 * t + 1);
    }
    {
        const float f[CHUNK] = {a1.x, a1.y, a1.z, a1.w, b1.x, b1.y, b1.z, b1.w};
        float acc = E1, o[CHUNK];
        #pragma unroll
        for (int j = CHUNK - 1; j >= 0; --j) { acc += f[j]; o[j] = acc; }
        f4 q0 = {o[0], o[1], o[2], o[3]};
        f4 q1 = {o[4], o[5], o[6], o[7]};
        __builtin_nontemporal_store(q0, outp4 + 2 * (TPB + t));
        __builtin_nontemporal_store(q1, outp4 + 2 * (TPB + t) + 1);
    }
}

extern "C" void kernel_launch(void* const* d_in, const int* in_sizes, int n_in,
                              void* d_out, int out_size, void* d_ws, size_t ws_size,
                              hipStream_t stream) {
    const float* x = (const float*)d_in[0];
    float* out = (float*)d_out;
    const int rows = in_sizes[0] / COLS;   // 16384
    revcumsum_rows<<<rows, TPB, 0, stream>>>(x, out);
}